// Round 4
// baseline (281.815 us; speedup 1.0000x reference)
//
#include <hip/hip_runtime.h>
#include <hip/hip_bf16.h>

typedef __attribute__((ext_vector_type(4))) float f32x4;
typedef __attribute__((ext_vector_type(8))) short bf16x8;
typedef __attribute__((ext_vector_type(4))) short bf16x4v;

#define M_DIM 8192
#define N_DIM 4096
#define K_DIM 4096
#define NX (M_DIM * K_DIM)
#define NW (N_DIM * K_DIM)

#define BM 256
#define BN 256
#define BK 64
#define NKT (K_DIM / BK)   /* 64 */
#define THREADS 512

#define GLOAD_LDS16(g, l)                                                        \
  __builtin_amdgcn_global_load_lds(                                              \
      (const __attribute__((address_space(1))) void*)(g),                        \
      (__attribute__((address_space(3))) void*)(l), 16, 0, 0)

// ---------------------------------------------------------------------------
// Pass 1: fp32 -> bf16 conversion of x and W into workspace.
// ---------------------------------------------------------------------------
__global__ __launch_bounds__(256) void convert_bf16(const float* __restrict__ x,
                                                    const float* __restrict__ w,
                                                    short* __restrict__ ws) {
  const long stride = (long)gridDim.x * blockDim.x;
  const long total8 = ((long)NX + NW) / 8;
  for (long i = blockIdx.x * (long)blockDim.x + threadIdx.x; i < total8; i += stride) {
    const long base = i * 8;
    const float* src = (base < NX) ? (x + base) : (w + (base - NX));
    short* dst = ws + base;
    f32x4 a = *(const f32x4*)src;
    f32x4 b = *(const f32x4*)(src + 4);
    bf16x8 o;
    o[0] = (short)__bfloat16_as_ushort(__float2bfloat16(a[0]));
    o[1] = (short)__bfloat16_as_ushort(__float2bfloat16(a[1]));
    o[2] = (short)__bfloat16_as_ushort(__float2bfloat16(a[2]));
    o[3] = (short)__bfloat16_as_ushort(__float2bfloat16(a[3]));
    o[4] = (short)__bfloat16_as_ushort(__float2bfloat16(b[0]));
    o[5] = (short)__bfloat16_as_ushort(__float2bfloat16(b[1]));
    o[6] = (short)__bfloat16_as_ushort(__float2bfloat16(b[2]));
    o[7] = (short)__bfloat16_as_ushort(__float2bfloat16(b[3]));
    *(bf16x8*)dst = o;
  }
}

// ---------------------------------------------------------------------------
// Pass 2: 256x256 bf16 GEMM, BK=64, 8 waves (2M x 4N), double-buffered LDS,
// read-ahead register pipeline (each phase prefetches the NEXT phase's
// fragments so ds_read latency hides under the 16-MFMA cluster),
// counted vmcnt(8), 8-slot XOR swizzle, XCD-aware block swizzle, setprio.
// Y = relu(X @ W^T + b)
//
// LDS per buffer (64 KiB): A rows 0-255 at [0,32KB), B rows 0-255 at
// [32KB,64KB); row-major 128 B rows, 8 slots of 16 B, phys = logical^(row&7).
// ---------------------------------------------------------------------------
__global__ __launch_bounds__(THREADS, 2) void gemm256_bf16(
    const short* __restrict__ Abf,   /* [M][K] bf16 */
    const short* __restrict__ Bbf,   /* [N][K] bf16 */
    const float* __restrict__ bias,
    float* __restrict__ Y) {
  __shared__ short lds[2 * 32768];   /* 128 KiB */
  char* const ldsb = (char*)lds;

  const int tid  = threadIdx.x;
  const int lane = tid & 63;
  const int wave = tid >> 6;       // 0..7
  const int wm   = wave >> 2;      // 0..1  (M half)
  const int wn   = wave & 3;       // 0..3  (N quarter)

  // XCD-aware swizzle: 512 wgs, 8 XCDs, 64 contiguous logical ids per XCD.
  const int lin = blockIdx.x + blockIdx.y * (N_DIM / BN);   // gridDim.x = 16
  const int swz = (lin & 7) * 64 + (lin >> 3);
  const int bx = swz & 15;         // N tile
  const int by = swz >> 4;         // M tile
  const long rowA0 = (long)by * BM;
  const long rowB0 = (long)bx * BN;

  // staging lane geometry: one GLOAD issue = 512 thr x 16 B = 64 rows x 128 B.
  // LDS linear row = is*64 + wave*8 + (lane>>3); phys slot = lane&7;
  // source col chunk = phys ^ (row&7) (inverse swizzle, pre-applied).
  const int sg_col = (((lane & 7) ^ ((lane >> 3) & 7)) << 3);
  const int s_row  = wave * 8 + (lane >> 3);

  const short* gA = Abf + (rowA0 + s_row) * (long)K_DIM + sg_col;
  const short* gB = Bbf + (rowB0 + s_row) * (long)K_DIM + sg_col;

  // fragment-read per-lane byte offsets: row = frag*16 + (lane&15),
  // phys = (kslot) ^ (lane&7), kslot = lane>>4 (kk0) / 4+(lane>>4) (kk1).
  const int offk0 = (lane & 15) * 128 + ((((lane >> 4)) ^ (lane & 7)) << 4);
  const int offk1 = (lane & 15) * 128 + (((4 + (lane >> 4)) ^ (lane & 7)) << 4);

#define STAGE_A(BOFF_, TT) do {                                                  \
    const short* g_ = gA + (long)(TT) * BK;                                      \
    _Pragma("unroll")                                                            \
    for (int is_ = 0; is_ < 4; ++is_)                                            \
      GLOAD_LDS16(g_ + (long)is_ * 64 * K_DIM,                                   \
                  ldsb + (BOFF_) + is_ * 8192 + wave * 1024);                    \
  } while (0)

#define STAGE_B(BOFF_, TT) do {                                                  \
    const short* g_ = gB + (long)(TT) * BK;                                      \
    _Pragma("unroll")                                                            \
    for (int is_ = 0; is_ < 4; ++is_)                                            \
      GLOAD_LDS16(g_ + (long)is_ * 64 * K_DIM,                                   \
                  ldsb + (BOFF_) + 32768 + is_ * 8192 + wave * 1024);            \
  } while (0)

#define PH_READ_A(DST, BOFF_, MADD) do {                                         \
    const char* pa_ = ldsb + (BOFF_) + wm * 16384 + (MADD);                      \
    _Pragma("unroll")                                                            \
    for (int m_ = 0; m_ < 4; ++m_) {                                             \
      DST[m_][0] = *(const bf16x8*)(pa_ + m_ * 2048 + offk0);                    \
      DST[m_][1] = *(const bf16x8*)(pa_ + m_ * 2048 + offk1);                    \
    }                                                                            \
  } while (0)

#define PH_READ_B(DST, BOFF_, NADD) do {                                         \
    const char* pb_ = ldsb + (BOFF_) + 32768 + wn * 8192 + (NADD);               \
    _Pragma("unroll")                                                            \
    for (int n_ = 0; n_ < 2; ++n_) {                                             \
      DST[n_][0] = *(const bf16x8*)(pb_ + n_ * 2048 + offk0);                    \
      DST[n_][1] = *(const bf16x8*)(pb_ + n_ * 2048 + offk1);                    \
    }                                                                            \
  } while (0)

#define MFMA16(AF, BF, MB, NB) do {                                              \
    __builtin_amdgcn_s_setprio(1);                                               \
    _Pragma("unroll")                                                            \
    for (int kk_ = 0; kk_ < 2; ++kk_)                                            \
      _Pragma("unroll")                                                          \
      for (int m_ = 0; m_ < 4; ++m_)                                             \
        _Pragma("unroll")                                                        \
        for (int n_ = 0; n_ < 2; ++n_)                                           \
          acc[(MB) + m_][(NB) + n_] = __builtin_amdgcn_mfma_f32_16x16x32_bf16(   \
              AF[m_][kk_], BF[n_][kk_], acc[(MB) + m_][(NB) + n_], 0, 0, 0);     \
    __builtin_amdgcn_s_setprio(0);                                               \
  } while (0)

// One K-tile (4 phases, 1 barrier each + 1 residence barrier in ph3).
// CUR holds m0-3 of tile T (read during previous ph3); ALT receives m4-7 of T
// at ph0 and then m0-3 of T+1 at ph3 (sequential reuse, no extra registers).
#define TILE(CUR, ALT, BOFF_, NOFF_, T, DO_ST, DO_PF, VM8) do {                  \
    /* ph0: prefetch A-hi(T); MFMA Q0 = (m0-3, n0-1) */                          \
    asm volatile("s_waitcnt lgkmcnt(0)" ::: "memory");                           \
    __builtin_amdgcn_sched_barrier(0);                                           \
    PH_READ_A(ALT, BOFF_, 8192);                                                 \
    __builtin_amdgcn_sched_barrier(0);                                           \
    MFMA16(CUR, bfr01, 0, 0);                                                    \
    __builtin_amdgcn_s_barrier();                                                \
    /* ph1: prefetch B23(T); MFMA Q1 = (m4-7, n0-1) */                           \
    asm volatile("s_waitcnt lgkmcnt(0)" ::: "memory");                           \
    __builtin_amdgcn_sched_barrier(0);                                           \
    PH_READ_B(bfr23, BOFF_, 4096);                                               \
    __builtin_amdgcn_sched_barrier(0);                                           \
    MFMA16(ALT, bfr01, 4, 0);                                                    \
    __builtin_amdgcn_s_barrier();                                                \
    /* ph2: stage A(T+2); MFMA Q2 = (m4-7, n2-3) */                              \
    asm volatile("s_waitcnt lgkmcnt(0)" ::: "memory");                           \
    __builtin_amdgcn_sched_barrier(0);                                           \
    if (DO_ST) STAGE_A(BOFF_, (T) + 2);                                          \
    __builtin_amdgcn_sched_barrier(0);                                           \
    MFMA16(ALT, bfr23, 4, 2);                                                    \
    __builtin_amdgcn_s_barrier();                                                \
    /* ph3: stage B(T+2); vmcnt -> barrier (cross-wave residence of T+1); */     \
    /* prefetch T+1 A-lo into ALT and B01; MFMA Q3 = (m0-3, n2-3) */             \
    if (DO_ST) STAGE_B(BOFF_, (T) + 2);                                          \
    if (DO_PF) {                                                                 \
      if (VM8) asm volatile("s_waitcnt vmcnt(8)" ::: "memory");                  \
      else     asm volatile("s_waitcnt vmcnt(0)" ::: "memory");                  \
      __builtin_amdgcn_s_barrier();                                              \
      __builtin_amdgcn_sched_barrier(0);                                         \
      PH_READ_A(ALT, NOFF_, 0);                                                  \
      PH_READ_B(bfr01, NOFF_, 0);                                                \
      __builtin_amdgcn_sched_barrier(0);                                         \
    }                                                                            \
    MFMA16(CUR, bfr23, 0, 2);                                                    \
  } while (0)

  f32x4 acc[8][4];
#pragma unroll
  for (int i = 0; i < 8; ++i)
#pragma unroll
    for (int j = 0; j < 4; ++j) acc[i][j] = (f32x4)0.0f;

  bf16x8 afA[4][2], afB[4][2], bfr01[2][2], bfr23[2][2];

  // ---- prologue: stage tiles 0,1 fully; read tile-0 (m0-3, n0-1) ----
  STAGE_A(0, 0);
  STAGE_B(0, 0);
  STAGE_A(65536, 1);
  STAGE_B(65536, 1);
  asm volatile("s_waitcnt vmcnt(8)" ::: "memory");   // tile 0 resident
  __builtin_amdgcn_s_barrier();
  __builtin_amdgcn_sched_barrier(0);
  PH_READ_A(afA, 0, 0);
  PH_READ_B(bfr01, 0, 0);
  __builtin_amdgcn_sched_barrier(0);

  // ---- main loop: 2 tiles per iteration, tiles 0..61 ----
  for (int tp = 0; tp < NKT / 2 - 1; ++tp) {
    const int t0 = 2 * tp;
    TILE(afA, afB, 0, 65536, t0, 1, 1, 1);
    TILE(afB, afA, 65536, 0, t0 + 1, 1, 1, 1);
  }
  // ---- tail: tiles 62, 63 ----
  TILE(afA, afB, 0, 65536, NKT - 2, 0, 1, 0);   // no stage; drain + prefetch 63
  TILE(afB, afA, 65536, 0, NKT - 1, 0, 0, 0);   // final tile

#undef TILE
#undef MFMA16
#undef PH_READ_B
#undef PH_READ_A
#undef STAGE_B
#undef STAGE_A

  // ---- epilogue: bias + relu, fp32 stores ----
  const int c0 = lane & 15;
  const int r0 = (lane >> 4) * 4;
#pragma unroll
  for (int j = 0; j < 4; ++j) {
    const long gc = rowB0 + wn * 64 + j * 16 + c0;
    const float bv = bias[gc];
#pragma unroll
    for (int i = 0; i < 8; ++i) {
      const long gr0 = rowA0 + wm * 128 + i * 16 + r0;
#pragma unroll
      for (int r = 0; r < 4; ++r) {
        float v = acc[i][j][r] + bv;
        Y[(gr0 + r) * (long)N_DIM + gc] = fmaxf(v, 0.0f);
      }
    }
  }
}

// ---------------------------------------------------------------------------
// Fallback (only if ws too small): fp32 reg-staged 128^2 kernel.
// ---------------------------------------------------------------------------
#define FBM 128
#define FBK 32
#define FLDSS 40
__global__ __launch_bounds__(256) void fallback_gemm(
    const float* __restrict__ X, const float* __restrict__ W,
    const float* __restrict__ bias, float* __restrict__ Y) {
  __shared__ short As[FBM * FLDSS];
  __shared__ short Bs[FBM * FLDSS];
  const int tid = threadIdx.x, lane = tid & 63, wave = tid >> 6;
  const int wm = (wave >> 1) * 64, wn = (wave & 1) * 64;
  const long rowA0 = (long)blockIdx.y * FBM, rowB0 = (long)blockIdx.x * FBM;
  const int srow = tid >> 3, scol = (tid & 7) * 4;
  const float* Aptr = X + (rowA0 + srow) * (long)K_DIM + scol;
  const float* Bptr = W + (rowB0 + srow) * (long)K_DIM + scol;
  f32x4 ra[4], rb[4];
#pragma unroll
  for (int i = 0; i < 4; ++i) {
    ra[i] = *(const f32x4*)(Aptr + (long)i * 32 * K_DIM);
    rb[i] = *(const f32x4*)(Bptr + (long)i * 32 * K_DIM);
  }
  f32x4 acc[4][4];
#pragma unroll
  for (int i = 0; i < 4; ++i)
#pragma unroll
    for (int j = 0; j < 4; ++j) acc[i][j] = (f32x4)0.0f;
  for (int kt = 0; kt < K_DIM / FBK; ++kt) {
    __syncthreads();
#pragma unroll
    for (int i = 0; i < 4; ++i) {
      bf16x4v pa, pb;
#pragma unroll
      for (int j = 0; j < 4; ++j) {
        pa[j] = (short)__bfloat16_as_ushort(__float2bfloat16(ra[i][j]));
        pb[j] = (short)__bfloat16_as_ushort(__float2bfloat16(rb[i][j]));
      }
      *(bf16x4v*)&As[(i * 32 + srow) * FLDSS + scol] = pa;
      *(bf16x4v*)&Bs[(i * 32 + srow) * FLDSS + scol] = pb;
    }
    if (kt + 1 < K_DIM / FBK) {
      const float* An = Aptr + (kt + 1) * FBK;
      const float* Bn = Bptr + (kt + 1) * FBK;
#pragma unroll
      for (int i = 0; i < 4; ++i) {
        ra[i] = *(const f32x4*)(An + (long)i * 32 * K_DIM);
        rb[i] = *(const f32x4*)(Bn + (long)i * 32 * K_DIM);
      }
    }
    __syncthreads();
    bf16x8 af[4], bfr[4];
#pragma unroll
    for (int i = 0; i < 4; ++i) {
      af[i]  = *(const bf16x8*)&As[(wm + i * 16 + (lane & 15)) * FLDSS + (lane >> 4) * 8];
      bfr[i] = *(const bf16x8*)&Bs[(wn + i * 16 + (lane & 15)) * FLDSS + (lane >> 4) * 8];
    }
#pragma unroll
    for (int i = 0; i < 4; ++i)
#pragma unroll
      for (int j = 0; j < 4; ++j)
        acc[i][j] = __builtin_amdgcn_mfma_f32_16x16x32_bf16(af[i], bfr[j], acc[i][j], 0, 0, 0);
  }
  const int r0 = (lane >> 4) * 4, c0 = lane & 15;
#pragma unroll
  for (int j = 0; j < 4; ++j) {
    const long gc = rowB0 + wn + j * 16 + c0;
    const float bv = bias[gc];
#pragma unroll
    for (int i = 0; i < 4; ++i) {
      const long gr0 = rowA0 + wm + i * 16 + r0;
#pragma unroll
      for (int r = 0; r < 4; ++r) {
        float v = acc[i][j][r] + bv;
        Y[(gr0 + r) * (long)N_DIM + gc] = fmaxf(v, 0.0f);
      }
    }
  }
}

extern "C" void kernel_launch(void* const* d_in, const int* in_sizes, int n_in,
                              void* d_out, int out_size, void* d_ws, size_t ws_size,
                              hipStream_t stream) {
  const float* x = (const float*)d_in[0];
  const float* w = (const float*)d_in[1];
  const float* b = (const float*)d_in[2];
  float* y = (float*)d_out;

  const size_t need = (size_t)(NX + NW) * sizeof(short);
  if (ws_size >= need) {
    short* ws = (short*)d_ws;
    convert_bf16<<<2048, 256, 0, stream>>>(x, w, ws);
    dim3 grid(N_DIM / BN, M_DIM / BM);
    gemm256_bf16<<<grid, dim3(THREADS), 0, stream>>>(ws, ws + NX, b, y);
  } else {
    dim3 grid(N_DIM / FBM, M_DIM / FBM);
    fallback_gemm<<<grid, dim3(256), 0, stream>>>(x, w, b, y);
  }
}